// Round 1
// baseline (3070.284 us; speedup 1.0000x reference)
//
#include <hip/hip_runtime.h>

#define NN 100000
#define NE 1600000
#define DD 128
#define GG 64
#define TM 32
#define BN_EPS 1e-5f

constexpr int SCAN_B = 1024;
constexpr int NB = (NN + SCAN_B - 1) / SCAN_B;  // 98

__device__ __forceinline__ unsigned enc_f(float v) {
  unsigned u = __float_as_uint(v);
  return (u & 0x80000000u) ? ~u : (u | 0x80000000u);
}
__device__ __forceinline__ float dec_f(unsigned k) {
  unsigned u = (k & 0x80000000u) ? (k & 0x7FFFFFFFu) : ~k;
  return __uint_as_float(u);
}

// ---------------- init: zero accumulators, set segmax identity ----------------
__global__ void k_init(float* agg_ef, int* deg, float* stats, unsigned* gemb_enc) {
  int i = blockIdx.x * blockDim.x + threadIdx.x;
  if (i < NN) {
    deg[i] = 0;
    agg_ef[i*3+0] = 0.f; agg_ef[i*3+1] = 0.f; agg_ef[i*3+2] = 0.f;
  }
  if (i < 7*2*DD) stats[i] = 0.f;
  if (i < GG*DD) gemb_enc[i] = 0x007FFFFFu;  // enc(-inf)
}

// ---------------- per-node edge-feature aggregation + in-degree ----------------
__global__ void k_edge_agg(const float* __restrict__ ef, const int* __restrict__ to,
                           float* agg_ef, int* deg) {
  int e = blockIdx.x * blockDim.x + threadIdx.x;
  if (e >= NE) return;
  int t = to[e];
  atomicAdd(&deg[t], 1);
  atomicAdd(&agg_ef[t*3+0], ef[e*3+0]);
  atomicAdd(&agg_ef[t*3+1], ef[e*3+1]);
  atomicAdd(&agg_ef[t*3+2], ef[e*3+2]);
}

// ---------------- CSR build: scan over deg ----------------
__global__ void k_scan1(const int* __restrict__ deg, int* row_ptr, int* bsum) {
  __shared__ int lds[SCAN_B];
  int t = threadIdx.x, i = blockIdx.x * SCAN_B + t;
  int v = (i < NN) ? deg[i] : 0;
  lds[t] = v;
  __syncthreads();
  for (int off = 1; off < SCAN_B; off <<= 1) {
    int add = (t >= off) ? lds[t - off] : 0;
    __syncthreads();
    lds[t] += add;
    __syncthreads();
  }
  if (i < NN) row_ptr[i] = lds[t] - v;  // exclusive within block
  if (t == SCAN_B - 1) bsum[blockIdx.x] = lds[t];
}

__global__ void k_scan2(const int* bsum, int* boff, int* row_ptr) {
  if (blockIdx.x == 0 && threadIdx.x == 0) {
    int run = 0;
    for (int b = 0; b < NB; ++b) { boff[b] = run; run += bsum[b]; }
    row_ptr[NN] = run;
  }
}

__global__ void k_scan3(int* row_ptr, const int* __restrict__ boff, int* cursor) {
  int i = blockIdx.x * blockDim.x + threadIdx.x;
  if (i >= NN) return;
  int v = row_ptr[i] + boff[i >> 10];
  row_ptr[i] = v;
  cursor[i] = v;
}

__global__ void k_fill(const int* __restrict__ from, const int* __restrict__ to,
                       int* cursor, int* __restrict__ csr_src) {
  int e = blockIdx.x * blockDim.x + threadIdx.x;
  if (e >= NE) return;
  int pos = atomicAdd(&cursor[to[e]], 1);
  csr_src[pos] = from[e];
}

// ---------------- neighbor gather: agg = scale*(sum_{e->n} R[src]) + deg*shift ----------------
__global__ void k_gather(const float* __restrict__ R, float* __restrict__ out,
                         const int* __restrict__ row_ptr, const int* __restrict__ csr_src,
                         const float* __restrict__ stats, const float* __restrict__ g,
                         const float* __restrict__ b) {
  const int n = blockIdx.x;
  const int d = threadIdx.x;
  const int s = row_ptr[n], e = row_ptr[n + 1];
  float acc = 0.f;
  int i = s;
  for (; i + 1 < e; i += 2) {
    int s0 = csr_src[i], s1 = csr_src[i + 1];
    acc += R[(size_t)s0 * DD + d];
    acc += R[(size_t)s1 * DD + d];
  }
  if (i < e) acc += R[(size_t)csr_src[i] * DD + d];
  float mean = stats[d] * (1.f / NN);
  float var  = stats[DD + d] * (1.f / NN) - mean * mean;
  float rs = rsqrtf(var + BN_EPS);
  float scale = g[d] * rs;
  float shift = b[d] - mean * scale;
  out[(size_t)n * DD + d] = scale * acc + shift * (float)(e - s);
}

// ---------------- fused GEMM: out = relu(norm?(in) @ W + bias + extra), + column stats ----------------
// MODE 0: extra = e2n from aggregated edge features (agg_ef @ w_e2l + deg*b_e2l)
// MODE 1: input normalized with in_stats/in_g/in_b; extra = BN-affine(resid) residual
template<int MODE>
__global__ __launch_bounds__(256, 2)
void k_gemm(const float* __restrict__ in, const float* __restrict__ W,
            const float* __restrict__ bias, float* __restrict__ out,
            float* __restrict__ stats_out,
            const float* __restrict__ in_stats, const float* __restrict__ in_g,
            const float* __restrict__ in_b,
            const float* __restrict__ resid, const float* __restrict__ res_stats,
            const float* __restrict__ res_g, const float* __restrict__ res_b,
            const float* __restrict__ agg_ef, const int* __restrict__ deg,
            const float* __restrict__ w_e2l, const float* __restrict__ b_e2l) {
  __shared__ float lds_in[TM][DD];   // 16 KB
  __shared__ float lds_w[DD][DD];    // 64 KB
  const int tid = threadIdx.x;
  const int row0 = blockIdx.x * TM;

  {  // stage W
    const float4* W4 = (const float4*)W;
    float4* lw4 = (float4*)lds_w;
    for (int i = tid; i < DD * DD / 4; i += 256) lw4[i] = W4[i];
  }
  {  // stage input tile (optionally BN-normalized)
    const int c4 = tid & 31;
    float ns[4], nh[4];
    if (MODE == 1) {
      for (int j = 0; j < 4; ++j) {
        int c = c4 * 4 + j;
        float mean = in_stats[c] * (1.f / NN);
        float var  = in_stats[DD + c] * (1.f / NN) - mean * mean;
        float rs = rsqrtf(var + BN_EPS);
        ns[j] = in_g[c] * rs;
        nh[j] = in_b[c] - mean * ns[j];
      }
    }
    const float4* in4 = (const float4*)in;
    for (int k = 0; k < 4; ++k) {
      int idx = tid + k * 256;
      int r = idx >> 5;
      float4 v = in4[(size_t)(row0 + r) * (DD / 4) + c4];
      if (MODE == 1) {
        v.x = ns[0] * v.x + nh[0]; v.y = ns[1] * v.y + nh[1];
        v.z = ns[2] * v.z + nh[2]; v.w = ns[3] * v.w + nh[3];
      }
      *(float4*)&lds_in[r][c4 * 4] = v;
    }
  }
  __syncthreads();

  const int tc = tid & 31, tr = tid >> 5;
  const int c0 = tc * 4, r0 = tr * 4;
  float acc[4][4];
  {
    float base_c[4];
    for (int j = 0; j < 4; ++j) base_c[j] = bias[c0 + j];
    if (MODE == 1) {
      float esc[4], esh[4];
      for (int j = 0; j < 4; ++j) {
        int c = c0 + j;
        float mean = res_stats[c] * (1.f / NN);
        float var  = res_stats[DD + c] * (1.f / NN) - mean * mean;
        float rs = rsqrtf(var + BN_EPS);
        esc[j] = res_g[c] * rs;
        esh[j] = res_b[c] - mean * esc[j];
      }
      for (int i = 0; i < 4; ++i) {
        int n = row0 + r0 + i;
        const float4 rv = *(const float4*)&resid[(size_t)n * DD + c0];
        acc[i][0] = base_c[0] + esc[0] * rv.x + esh[0];
        acc[i][1] = base_c[1] + esc[1] * rv.y + esh[1];
        acc[i][2] = base_c[2] + esc[2] * rv.z + esh[2];
        acc[i][3] = base_c[3] + esc[3] * rv.w + esh[3];
      }
    } else {
      float wc0[4], wc1[4], wc2[4], bc[4];
      for (int j = 0; j < 4; ++j) {
        wc0[j] = w_e2l[c0 + j];
        wc1[j] = w_e2l[DD + c0 + j];
        wc2[j] = w_e2l[2 * DD + c0 + j];
        bc[j]  = b_e2l[c0 + j];
      }
      for (int i = 0; i < 4; ++i) {
        int n = row0 + r0 + i;
        float e0 = agg_ef[n*3+0], e1 = agg_ef[n*3+1], e2 = agg_ef[n*3+2];
        float dg = (float)deg[n];
        for (int j = 0; j < 4; ++j)
          acc[i][j] = base_c[j] + e0 * wc0[j] + e1 * wc1[j] + e2 * wc2[j] + dg * bc[j];
      }
    }
  }

  for (int d = 0; d < DD; d += 4) {
    float4 a0 = *(const float4*)&lds_in[r0 + 0][d];
    float4 a1 = *(const float4*)&lds_in[r0 + 1][d];
    float4 a2 = *(const float4*)&lds_in[r0 + 2][d];
    float4 a3 = *(const float4*)&lds_in[r0 + 3][d];
    float4 w0 = *(const float4*)&lds_w[d + 0][c0];
    float4 w1 = *(const float4*)&lds_w[d + 1][c0];
    float4 w2 = *(const float4*)&lds_w[d + 2][c0];
    float4 w3 = *(const float4*)&lds_w[d + 3][c0];
#define STEP(ai, i)                                                 \
    acc[i][0] += ai.x*w0.x + ai.y*w1.x + ai.z*w2.x + ai.w*w3.x;     \
    acc[i][1] += ai.x*w0.y + ai.y*w1.y + ai.z*w2.y + ai.w*w3.y;     \
    acc[i][2] += ai.x*w0.z + ai.y*w1.z + ai.z*w2.z + ai.w*w3.z;     \
    acc[i][3] += ai.x*w0.w + ai.y*w1.w + ai.z*w2.w + ai.w*w3.w;
    STEP(a0, 0) STEP(a1, 1) STEP(a2, 2) STEP(a3, 3)
#undef STEP
  }

  for (int i = 0; i < 4; ++i) {
    for (int j = 0; j < 4; ++j) acc[i][j] = fmaxf(acc[i][j], 0.f);
    int n = row0 + r0 + i;
    *(float4*)&out[(size_t)n * DD + c0] =
        make_float4(acc[i][0], acc[i][1], acc[i][2], acc[i][3]);
  }

  // column stats for the following BN
  __syncthreads();
  float* red = &lds_in[0][0];  // 2048 floats: [0..1023]=sum, [1024..2047]=sumsq
  for (int j = 0; j < 4; ++j) {
    float s = 0.f, s2 = 0.f;
    for (int i = 0; i < 4; ++i) { float v = acc[i][j]; s += v; s2 += v * v; }
    red[tr * DD + c0 + j] = s;
    red[1024 + tr * DD + c0 + j] = s2;
  }
  __syncthreads();
  if (tr == 0) {
    for (int j = 0; j < 4; ++j) {
      int c = c0 + j;
      float s = 0.f, s2 = 0.f;
      for (int k = 0; k < 8; ++k) { s += red[k * DD + c]; s2 += red[1024 + k * DD + c]; }
      atomicAdd(&stats_out[c], s);
      atomicAdd(&stats_out[DD + c], s2);
    }
  }
}

// ---------------- segment max (g_idx sorted -> run compression) ----------------
__global__ void k_segmax(const float* __restrict__ R, const int* __restrict__ g_idx,
                         unsigned* __restrict__ gemb_enc,
                         const float* __restrict__ stats, const float* __restrict__ g,
                         const float* __restrict__ b) {
  int t = blockIdx.x * blockDim.x + threadIdx.x;
  int d = t & (DD - 1);
  int chunk = t >> 7;
  int n0 = chunk * 8;
  if (n0 >= NN) return;
  float mean = stats[d] * (1.f / NN);
  float var  = stats[DD + d] * (1.f / NN) - mean * mean;
  float rs = rsqrtf(var + BN_EPS);
  float scale = g[d] * rs;
  float shift = b[d] - mean * scale;
  int cur = -1; float run = 0.f;
  int nend = n0 + 8; if (nend > NN) nend = NN;
  for (int n = n0; n < nend; ++n) {
    float v = scale * R[(size_t)n * DD + d] + shift;
    int gi = g_idx[n];
    if (gi != cur) {
      if (cur >= 0) atomicMax(&gemb_enc[cur * DD + d], enc_f(run));
      cur = gi; run = v;
    } else {
      run = fmaxf(run, v);
    }
  }
  if (cur >= 0) atomicMax(&gemb_enc[cur * DD + d], enc_f(run));
}

// ---------------- readout: relu(gemb @ W + b) ----------------
__global__ void k_readout(const unsigned* __restrict__ gemb,
                          const float* __restrict__ W, const float* __restrict__ b,
                          float* __restrict__ out) {
  __shared__ float row[DD];
  int g = blockIdx.x, t = threadIdx.x;
  row[t] = dec_f(gemb[g * DD + t]);
  __syncthreads();
  float acc = b[t];
  for (int d = 0; d < DD; ++d) acc += row[d] * W[d * DD + t];
  out[g * DD + t] = fmaxf(acc, 0.f);
}

extern "C" void kernel_launch(void* const* d_in, const int* in_sizes, int n_in,
                              void* d_out, int out_size, void* d_ws, size_t ws_size,
                              hipStream_t stream) {
  const float* node_feat = (const float*)d_in[0];
  const float* edge_feat = (const float*)d_in[1];
  const int*   efrom     = (const int*)d_in[2];
  const int*   eto       = (const int*)d_in[3];
  const int*   g_idx     = (const int*)d_in[4];
  const float* w_n2l_w   = (const float*)d_in[6];
  const float* w_n2l_b   = (const float*)d_in[7];
  const float* w_e2l_w   = (const float*)d_in[8];   // [4][3][128]
  const float* w_e2l_b   = (const float*)d_in[9];   // [4][128]
  const float* conv_w    = (const float*)d_in[10];  // [3][128][128]
  const float* conv_b    = (const float*)d_in[11];
  const float* l2_w      = (const float*)d_in[12];
  const float* l2_b      = (const float*)d_in[13];
  const float* msg_bn_g  = (const float*)d_in[14];  // [4][128]
  const float* msg_bn_b  = (const float*)d_in[15];
  const float* hid_bn_g  = (const float*)d_in[16];  // [3][128]
  const float* hid_bn_b  = (const float*)d_in[17];
  const float* readout_w = (const float*)d_in[18];
  const float* readout_b = (const float*)d_in[19];
  float* out = (float*)d_out;
  (void)in_sizes; (void)n_in; (void)out_size; (void)ws_size;

  char* ws = (char*)d_ws;
  size_t off = 0;
  auto alloc = [&](size_t bytes) -> void* {
    void* p = ws + off; off += (bytes + 511) & ~(size_t)511; return p;
  };
  float*    P0      = (float*)alloc((size_t)NN * DD * 4);
  float*    P1      = (float*)alloc((size_t)NN * DD * 4);
  float*    P2      = (float*)alloc((size_t)NN * DD * 4);
  float*    agg_ef  = (float*)alloc((size_t)NN * 3 * 4);
  int*      deg     = (int*)alloc((size_t)NN * 4);
  int*      row_ptr = (int*)alloc((size_t)(NN + 1) * 4);
  int*      cursor  = (int*)alloc((size_t)NN * 4);
  int*      csr_src = (int*)alloc((size_t)NE * 4);
  int*      bsum    = (int*)alloc((size_t)NB * 4);
  int*      boff    = (int*)alloc((size_t)NB * 4);
  float*    stats   = (float*)alloc((size_t)7 * 2 * DD * 4);
  unsigned* gemb    = (unsigned*)alloc((size_t)GG * DD * 4);

  k_init<<<(NN + 255) / 256, 256, 0, stream>>>(agg_ef, deg, stats, gemb);
  k_edge_agg<<<(NE + 255) / 256, 256, 0, stream>>>(edge_feat, eto, agg_ef, deg);
  k_scan1<<<NB, SCAN_B, 0, stream>>>(deg, row_ptr, bsum);
  k_scan2<<<1, 64, 0, stream>>>(bsum, boff, row_ptr);
  k_scan3<<<(NN + 255) / 256, 256, 0, stream>>>(row_ptr, boff, cursor);
  k_fill<<<(NE + 255) / 256, 256, 0, stream>>>(efrom, eto, cursor, csr_src);

  float* stat_msg[4] = { stats + 0*256, stats + 1*256, stats + 2*256, stats + 3*256 };
  float* stat_hid[3] = { stats + 4*256, stats + 5*256, stats + 6*256 };

  // R0 = relu(node_feat @ w_n2l + b + e2n0); stats -> msg[0]
  k_gemm<0><<<NN / TM, 256, 0, stream>>>(
      node_feat, w_n2l_w, w_n2l_b, P0, stat_msg[0],
      nullptr, nullptr, nullptr, nullptr, nullptr, nullptr, nullptr,
      agg_ef, deg, w_e2l_w + 0 * 3 * DD, w_e2l_b + 0 * DD);

  float* R = P0; float* other = P1;
  for (int lv = 0; lv < 3; ++lv) {
    // agg = BN-affine_msg[lv]( seg(h[from]) )
    k_gather<<<NN, DD, 0, stream>>>(R, other, row_ptr, csr_src,
        stat_msg[lv], msg_bn_g + lv * DD, msg_bn_b + lv * DD);
    // x = relu(agg @ conv_w[lv] + conv_b + e2n[lv+1]); stats -> hid[lv]
    k_gemm<0><<<NN / TM, 256, 0, stream>>>(
        other, conv_w + (size_t)lv * DD * DD, conv_b + lv * DD, P2, stat_hid[lv],
        nullptr, nullptr, nullptr, nullptr, nullptr, nullptr, nullptr,
        agg_ef, deg, w_e2l_w + (size_t)(lv + 1) * 3 * DD, w_e2l_b + (lv + 1) * DD);
    // R_new = relu(normhid(x) @ l2_w[lv] + l2_b + affine_msg[lv](R)); stats -> msg[lv+1]
    k_gemm<1><<<NN / TM, 256, 0, stream>>>(
        P2, l2_w + (size_t)lv * DD * DD, l2_b + lv * DD, other, stat_msg[lv + 1],
        stat_hid[lv], hid_bn_g + lv * DD, hid_bn_b + lv * DD,
        R, stat_msg[lv], msg_bn_g + lv * DD, msg_bn_b + lv * DD,
        nullptr, nullptr, nullptr, nullptr);
    float* t = R; R = other; other = t;
  }

  // gemb = segment_max(affine_msg[3](R), g_idx); out = relu(gemb @ readout_w + b)
  k_segmax<<<(NN / 8) * DD / 256, 256, 0, stream>>>(
      R, g_idx, gemb, stat_msg[3], msg_bn_g + 3 * DD, msg_bn_b + 3 * DD);
  k_readout<<<GG, DD, 0, stream>>>(gemb, readout_w, readout_b, out);
}

// Round 2
// 1129.945 us; speedup vs baseline: 2.7172x; 2.7172x over previous
//
#include <hip/hip_runtime.h>
#include <hip/hip_bf16.h>

#define NN 100000
#define NE 1600000
#define DD 128
#define GG 64
#define BN_EPS 1e-5f

typedef unsigned short u16;
using f32x4 = __attribute__((ext_vector_type(4))) float;
using s16x8 = __attribute__((ext_vector_type(8))) short;

constexpr int SCAN_B = 1024;
constexpr int NB = (NN + SCAN_B - 1) / SCAN_B;  // 98

__device__ __forceinline__ unsigned enc_f(float v) {
  unsigned u = __float_as_uint(v);
  return (u & 0x80000000u) ? ~u : (u | 0x80000000u);
}
__device__ __forceinline__ float dec_f(unsigned k) {
  unsigned u = (k & 0x80000000u) ? (k & 0x7FFFFFFFu) : ~k;
  return __uint_as_float(u);
}
__device__ __forceinline__ u16 f2b(float x) {
  __hip_bfloat16 h = __float2bfloat16(x);
  return *(u16*)&h;
}
__device__ __forceinline__ float b2f(u16 u) {
  unsigned v = ((unsigned)u) << 16;
  return __uint_as_float(v);
}

// ---------------- init ----------------
__global__ void k_init(float* agg_ef, int* deg, float* stats, unsigned* gemb_enc) {
  int i = blockIdx.x * blockDim.x + threadIdx.x;
  if (i < NN) {
    deg[i] = 0;
    agg_ef[i*3+0] = 0.f; agg_ef[i*3+1] = 0.f; agg_ef[i*3+2] = 0.f;
  }
  if (i < 7*2*DD) stats[i] = 0.f;
  if (i < GG*DD) gemb_enc[i] = 0x007FFFFFu;  // enc(-inf)
}

// ---------------- fp32 -> bf16 convert (node features) ----------------
__global__ void k_cvt(const float4* __restrict__ in, u16* __restrict__ out) {
  int i = blockIdx.x * blockDim.x + threadIdx.x;
  if (i >= NN * DD / 4) return;
  float4 v = in[i];
  ushort4 o;
  o.x = f2b(v.x); o.y = f2b(v.y); o.z = f2b(v.z); o.w = f2b(v.w);
  *(ushort4*)(out + (size_t)i * 4) = o;
}

// ---------------- per-node edge-feature aggregation + in-degree ----------------
__global__ void k_edge_agg(const float* __restrict__ ef, const int* __restrict__ to,
                           float* agg_ef, int* deg) {
  int e = blockIdx.x * blockDim.x + threadIdx.x;
  if (e >= NE) return;
  int t = to[e];
  atomicAdd(&deg[t], 1);
  atomicAdd(&agg_ef[t*3+0], ef[e*3+0]);
  atomicAdd(&agg_ef[t*3+1], ef[e*3+1]);
  atomicAdd(&agg_ef[t*3+2], ef[e*3+2]);
}

// ---------------- CSR build ----------------
__global__ void k_scan1(const int* __restrict__ deg, int* row_ptr, int* bsum) {
  __shared__ int lds[SCAN_B];
  int t = threadIdx.x, i = blockIdx.x * SCAN_B + t;
  int v = (i < NN) ? deg[i] : 0;
  lds[t] = v;
  __syncthreads();
  for (int off = 1; off < SCAN_B; off <<= 1) {
    int add = (t >= off) ? lds[t - off] : 0;
    __syncthreads();
    lds[t] += add;
    __syncthreads();
  }
  if (i < NN) row_ptr[i] = lds[t] - v;
  if (t == SCAN_B - 1) bsum[blockIdx.x] = lds[t];
}

__global__ void k_scan2(const int* bsum, int* boff, int* row_ptr) {
  if (blockIdx.x == 0 && threadIdx.x == 0) {
    int run = 0;
    for (int b = 0; b < NB; ++b) { boff[b] = run; run += bsum[b]; }
    row_ptr[NN] = run;
  }
}

__global__ void k_scan3(int* row_ptr, const int* __restrict__ boff, int* cursor) {
  int i = blockIdx.x * blockDim.x + threadIdx.x;
  if (i >= NN) return;
  int v = row_ptr[i] + boff[i >> 10];
  row_ptr[i] = v;
  cursor[i] = v;
}

__global__ void k_fill(const int* __restrict__ from, const int* __restrict__ to,
                       int* cursor, int* __restrict__ csr_src) {
  int e = blockIdx.x * blockDim.x + threadIdx.x;
  if (e >= NE) return;
  int pos = atomicAdd(&cursor[to[e]], 1);
  csr_src[pos] = from[e];
}

// ---------------- neighbor gather (bf16 in/out) ----------------
__global__ void k_gather(const u16* __restrict__ R, u16* __restrict__ out,
                         const int* __restrict__ row_ptr, const int* __restrict__ csr_src,
                         const float* __restrict__ stats, const float* __restrict__ g,
                         const float* __restrict__ b) {
  const int n = blockIdx.x;
  const int d = threadIdx.x;
  const int s = row_ptr[n], e = row_ptr[n + 1];
  float acc = 0.f;
  int i = s;
  for (; i + 1 < e; i += 2) {
    int s0 = csr_src[i], s1 = csr_src[i + 1];
    acc += b2f(R[(size_t)s0 * DD + d]);
    acc += b2f(R[(size_t)s1 * DD + d]);
  }
  if (i < e) acc += b2f(R[(size_t)csr_src[i] * DD + d]);
  float mean = stats[d] * (1.f / NN);
  float var  = stats[DD + d] * (1.f / NN) - mean * mean;
  float rs = rsqrtf(var + BN_EPS);
  float scale = g[d] * rs;
  float shift = b[d] - mean * scale;
  out[(size_t)n * DD + d] = f2b(scale * acc + shift * (float)(e - s));
}

// ---------------- weight prep: WT[n][k] = bf16(W[k][n]*s_k); biasP = bias + t.W ----------------
// MODE 1 folds input-BN (from in_stats/in_g/in_b) into weights; also precomputes
// residual affine (esc, esh) from res_stats into rese[0..127]=esc, [128..255]=esh.
template<int MODE>
__global__ void k_wprep(const float* __restrict__ W, const float* __restrict__ bias,
                        const float* __restrict__ in_stats, const float* __restrict__ in_g,
                        const float* __restrict__ in_b,
                        const float* __restrict__ res_stats, const float* __restrict__ res_g,
                        const float* __restrict__ res_b,
                        u16* __restrict__ WT, float* __restrict__ biasP,
                        float* __restrict__ rese) {
  __shared__ float s_s[DD], s_t[DD];
  int t = threadIdx.x;
  if (t < DD) {
    float s = 1.f, tt = 0.f;
    if (MODE == 1) {
      float mean = in_stats[t] * (1.f / NN);
      float var  = in_stats[DD + t] * (1.f / NN) - mean * mean;
      float rs = rsqrtf(var + BN_EPS);
      s = in_g[t] * rs;
      tt = in_b[t] - mean * s;
      float m2 = res_stats[t] * (1.f / NN);
      float v2 = res_stats[DD + t] * (1.f / NN) - m2 * m2;
      float r2 = rsqrtf(v2 + BN_EPS);
      float sc = res_g[t] * r2;
      rese[t] = sc;
      rese[DD + t] = res_b[t] - m2 * sc;
    }
    s_s[t] = s; s_t[t] = tt;
  }
  __syncthreads();
  for (int idx = t; idx < DD * DD; idx += 256) {
    int k = idx >> 7, n = idx & 127;
    WT[n * DD + k] = f2b(W[idx] * s_s[k]);
  }
  if (t < DD) {
    float acc = bias[t];
    if (MODE == 1)
      for (int k = 0; k < DD; ++k) acc += s_t[k] * W[k * DD + t];
    biasP[t] = acc;
  }
}

// swizzled LDS byte address: granule XOR within 8-granule (128B) halves of a 256B row
__device__ __forceinline__ int swz_addr(int row_bytes, int xr, int g, int o) {
  return row_bytes + ((((g & 7) ^ xr) | (g & 8)) << 4) + o;
}

// ---------------- MFMA GEMM: out = relu(A @ Wfold + biasP + extra), raw bf16 + fp32 col stats ----------------
// MODE 0: extra = e2n (agg_ef @ w_e2l + deg*b_e2l)     MODE 1: extra = affine(resid)
template<int MODE>
__global__ __launch_bounds__(256, 2)
void k_gemm(const u16* __restrict__ A, const u16* __restrict__ WT,
            const float* __restrict__ biasP, u16* __restrict__ out,
            float* __restrict__ stats_out,
            const float* __restrict__ rese, const u16* __restrict__ resid,
            const float* __restrict__ agg_ef, const int* __restrict__ deg,
            const float* __restrict__ w_e2l, const float* __restrict__ b_e2l) {
  __shared__ u16 lds_a[128 * 128];   // 32 KB, swizzled
  __shared__ u16 lds_b[128 * 128];   // 32 KB, swizzled (WT = W^T, [n][k])
  __shared__ float sstats[2 * DD];
  const int tid  = threadIdx.x;
  const int lane = tid & 63;
  const int wv   = tid >> 6;
  const int row0 = blockIdx.x * 128;

  if (tid < 2 * DD) sstats[tid] = 0.f;

  // ---- stage A and WT: linear LDS dest, swizzled global source (m173) ----
#pragma unroll
  for (int c = 0; c < 8; ++c) {
    int gidx = (wv * 8 + c) * 64 + lane;          // granule index 0..2047
    int row = gidx >> 4, gL = gidx & 15;
    int gS = (gL & 8) | ((gL & 7) ^ (row & 7));
    int arow = row0 + row; if (arow >= NN) arow = NN - 1;
    const u16* gsrcA = A  + (size_t)arow * DD + gS * 8;
    const u16* gsrcB = WT + (size_t)row  * DD + gS * 8;
    u16* ldstA = lds_a + (size_t)(wv * 8 + c) * 512;
    u16* ldstB = lds_b + (size_t)(wv * 8 + c) * 512;
    __builtin_amdgcn_global_load_lds(
        (const __attribute__((address_space(1))) unsigned int*)gsrcA,
        (__attribute__((address_space(3))) unsigned int*)ldstA, 16, 0, 0);
    __builtin_amdgcn_global_load_lds(
        (const __attribute__((address_space(1))) unsigned int*)gsrcB,
        (__attribute__((address_space(3))) unsigned int*)ldstB, 16, 0, 0);
  }
  __syncthreads();

  const int colid = lane & 15;
  const int lgrp  = lane >> 4;
  const int rowbase = wv * 32;
  const int o = (lgrp & 1) * 8;

  // preload A fragments: afr[rf][ks]
  s16x8 afr[2][4];
#pragma unroll
  for (int rf = 0; rf < 2; ++rf) {
    int r = rowbase + rf * 16 + colid;
    int rb = r << 8, xr = r & 7;
#pragma unroll
    for (int ks = 0; ks < 4; ++ks) {
      int g0 = ks * 4 + (lgrp >> 1);
      uint2 lo = *(const uint2*)((const char*)lds_a + swz_addr(rb, xr, g0, o));
      uint2 hi = *(const uint2*)((const char*)lds_a + swz_addr(rb, xr, g0 + 2, o));
      union { unsigned u[4]; s16x8 v; } pk;
      pk.u[0] = lo.x; pk.u[1] = lo.y; pk.u[2] = hi.x; pk.u[3] = hi.y;
      afr[rf][ks] = pk.v;
    }
  }

  // hoist per-row e2n inputs (MODE 0)
  float ev[2][4][4];
  if (MODE == 0) {
#pragma unroll
    for (int rf = 0; rf < 2; ++rf)
#pragma unroll
      for (int q = 0; q < 4; ++q) {
        int r = row0 + rowbase + rf * 16 + lgrp * 4 + q;
        if (r >= NN) r = NN - 1;
        ev[rf][q][0] = agg_ef[r*3+0];
        ev[rf][q][1] = agg_ef[r*3+1];
        ev[rf][q][2] = agg_ef[r*3+2];
        ev[rf][q][3] = (float)deg[r];
      }
  }

  for (int cf = 0; cf < 8; ++cf) {
    const int col = cf * 16 + colid;
    float bp = biasP[col];
    f32x4 acc0, acc1;
    if (MODE == 1) {
      float sc = rese[col], sh = rese[DD + col];
#pragma unroll
      for (int rf = 0; rf < 2; ++rf)
#pragma unroll
        for (int q = 0; q < 4; ++q) {
          int r = row0 + rowbase + rf * 16 + lgrp * 4 + q;
          int rc = r < NN ? r : NN - 1;
          float v = bp + sc * b2f(resid[(size_t)rc * DD + col]) + sh;
          if (rf == 0) acc0[q] = v; else acc1[q] = v;
        }
    } else {
      float we0 = w_e2l[col], we1 = w_e2l[DD + col], we2 = w_e2l[2 * DD + col];
      float be = b_e2l[col];
#pragma unroll
      for (int rf = 0; rf < 2; ++rf)
#pragma unroll
        for (int q = 0; q < 4; ++q) {
          float v = bp + ev[rf][q][0]*we0 + ev[rf][q][1]*we1 + ev[rf][q][2]*we2
                       + ev[rf][q][3]*be;
          if (rf == 0) acc0[q] = v; else acc1[q] = v;
        }
    }
    {
      int nb = col << 8, xn = col & 7;
#pragma unroll
      for (int ks = 0; ks < 4; ++ks) {
        int g0 = ks * 4 + (lgrp >> 1);
        uint2 lo = *(const uint2*)((const char*)lds_b + swz_addr(nb, xn, g0, o));
        uint2 hi = *(const uint2*)((const char*)lds_b + swz_addr(nb, xn, g0 + 2, o));
        union { unsigned u[4]; s16x8 v; } pk;
        pk.u[0] = lo.x; pk.u[1] = lo.y; pk.u[2] = hi.x; pk.u[3] = hi.y;
        acc0 = __builtin_amdgcn_mfma_f32_16x16x32_bf16(afr[0][ks], pk.v, acc0, 0, 0, 0);
        acc1 = __builtin_amdgcn_mfma_f32_16x16x32_bf16(afr[1][ks], pk.v, acc1, 0, 0, 0);
      }
    }
    // epilogue: relu, bf16 store, fp32 column stats
    float s = 0.f, s2 = 0.f;
#pragma unroll
    for (int rf = 0; rf < 2; ++rf)
#pragma unroll
      for (int q = 0; q < 4; ++q) {
        int r = row0 + rowbase + rf * 16 + lgrp * 4 + q;
        float v = fmaxf(rf == 0 ? acc0[q] : acc1[q], 0.f);
        if (r < NN) {
          out[(size_t)r * DD + col] = f2b(v);
          s += v; s2 += v * v;
        }
      }
    s  += __shfl_xor(s, 16);  s  += __shfl_xor(s, 32);
    s2 += __shfl_xor(s2, 16); s2 += __shfl_xor(s2, 32);
    if (lgrp == 0) {
      atomicAdd(&sstats[col], s);
      atomicAdd(&sstats[DD + col], s2);
    }
  }
  __syncthreads();
  if (tid < 2 * DD) atomicAdd(&stats_out[tid], sstats[tid]);
}

// ---------------- segment max (bf16 input) ----------------
__global__ void k_segmax(const u16* __restrict__ R, const int* __restrict__ g_idx,
                         unsigned* __restrict__ gemb_enc,
                         const float* __restrict__ stats, const float* __restrict__ g,
                         const float* __restrict__ b) {
  int t = blockIdx.x * blockDim.x + threadIdx.x;
  int d = t & (DD - 1);
  int chunk = t >> 7;
  int n0 = chunk * 8;
  if (n0 >= NN) return;
  float mean = stats[d] * (1.f / NN);
  float var  = stats[DD + d] * (1.f / NN) - mean * mean;
  float rs = rsqrtf(var + BN_EPS);
  float scale = g[d] * rs;
  float shift = b[d] - mean * scale;
  int cur = -1; float run = 0.f;
  int nend = n0 + 8; if (nend > NN) nend = NN;
  for (int n = n0; n < nend; ++n) {
    float v = scale * b2f(R[(size_t)n * DD + d]) + shift;
    int gi = g_idx[n];
    if (gi != cur) {
      if (cur >= 0) atomicMax(&gemb_enc[cur * DD + d], enc_f(run));
      cur = gi; run = v;
    } else {
      run = fmaxf(run, v);
    }
  }
  if (cur >= 0) atomicMax(&gemb_enc[cur * DD + d], enc_f(run));
}

// ---------------- readout ----------------
__global__ void k_readout(const unsigned* __restrict__ gemb,
                          const float* __restrict__ W, const float* __restrict__ b,
                          float* __restrict__ out) {
  __shared__ float row[DD];
  int g = blockIdx.x, t = threadIdx.x;
  row[t] = dec_f(gemb[g * DD + t]);
  __syncthreads();
  float acc = b[t];
  for (int d = 0; d < DD; ++d) acc += row[d] * W[d * DD + t];
  out[g * DD + t] = fmaxf(acc, 0.f);
}

extern "C" void kernel_launch(void* const* d_in, const int* in_sizes, int n_in,
                              void* d_out, int out_size, void* d_ws, size_t ws_size,
                              hipStream_t stream) {
  const float* node_feat = (const float*)d_in[0];
  const float* edge_feat = (const float*)d_in[1];
  const int*   efrom     = (const int*)d_in[2];
  const int*   eto       = (const int*)d_in[3];
  const int*   g_idx     = (const int*)d_in[4];
  const float* w_n2l_w   = (const float*)d_in[6];
  const float* w_n2l_b   = (const float*)d_in[7];
  const float* w_e2l_w   = (const float*)d_in[8];   // [4][3][128]
  const float* w_e2l_b   = (const float*)d_in[9];   // [4][128]
  const float* conv_w    = (const float*)d_in[10];  // [3][128][128]
  const float* conv_b    = (const float*)d_in[11];
  const float* l2_w      = (const float*)d_in[12];
  const float* l2_b      = (const float*)d_in[13];
  const float* msg_bn_g  = (const float*)d_in[14];  // [4][128]
  const float* msg_bn_b  = (const float*)d_in[15];
  const float* hid_bn_g  = (const float*)d_in[16];  // [3][128]
  const float* hid_bn_b  = (const float*)d_in[17];
  const float* readout_w = (const float*)d_in[18];
  const float* readout_b = (const float*)d_in[19];
  float* out = (float*)d_out;
  (void)in_sizes; (void)n_in; (void)out_size; (void)ws_size;

  char* ws = (char*)d_ws;
  size_t off = 0;
  auto alloc = [&](size_t bytes) -> void* {
    void* p = ws + off; off += (bytes + 511) & ~(size_t)511; return p;
  };
  u16*      node_bf = (u16*)alloc((size_t)NN * DD * 2);
  u16*      Pb0     = (u16*)alloc((size_t)NN * DD * 2);
  u16*      Pb1     = (u16*)alloc((size_t)NN * DD * 2);
  u16*      Pb2     = (u16*)alloc((size_t)NN * DD * 2);
  float*    agg_ef  = (float*)alloc((size_t)NN * 3 * 4);
  int*      deg     = (int*)alloc((size_t)NN * 4);
  int*      row_ptr = (int*)alloc((size_t)(NN + 1) * 4);
  int*      cursor  = (int*)alloc((size_t)NN * 4);
  int*      csr_src = (int*)alloc((size_t)NE * 4);
  int*      bsum    = (int*)alloc((size_t)NB * 4);
  int*      boff    = (int*)alloc((size_t)NB * 4);
  float*    stats   = (float*)alloc((size_t)7 * 2 * DD * 4);
  unsigned* gemb    = (unsigned*)alloc((size_t)GG * DD * 4);
  u16*      wt[7];
  float*    bp[7];
  float*    re[7];
  for (int i = 0; i < 7; ++i) {
    wt[i] = (u16*)alloc((size_t)DD * DD * 2);
    bp[i] = (float*)alloc((size_t)DD * 4);
    re[i] = (float*)alloc((size_t)2 * DD * 4);
  }

  k_init<<<(NN + 255) / 256, 256, 0, stream>>>(agg_ef, deg, stats, gemb);
  k_cvt<<<(NN * DD / 4 + 255) / 256, 256, 0, stream>>>((const float4*)node_feat, node_bf);
  k_edge_agg<<<(NE + 255) / 256, 256, 0, stream>>>(edge_feat, eto, agg_ef, deg);
  k_scan1<<<NB, SCAN_B, 0, stream>>>(deg, row_ptr, bsum);
  k_scan2<<<1, 64, 0, stream>>>(bsum, boff, row_ptr);
  k_scan3<<<(NN + 255) / 256, 256, 0, stream>>>(row_ptr, boff, cursor);
  k_fill<<<(NE + 255) / 256, 256, 0, stream>>>(efrom, eto, cursor, csr_src);

  float* stat_msg[4] = { stats + 0*256, stats + 1*256, stats + 2*256, stats + 3*256 };
  float* stat_hid[3] = { stats + 4*256, stats + 5*256, stats + 6*256 };
  const int GEMM_GRID = (NN + 127) / 128;  // 782

  // GEMM0: P0 = relu(node @ w_n2l + b + e2n0); stats -> msg[0]
  k_wprep<0><<<1, 256, 0, stream>>>(w_n2l_w, w_n2l_b,
      nullptr, nullptr, nullptr, nullptr, nullptr, nullptr, wt[0], bp[0], re[0]);
  k_gemm<0><<<GEMM_GRID, 256, 0, stream>>>(node_bf, wt[0], bp[0], Pb0, stat_msg[0],
      nullptr, nullptr, agg_ef, deg, w_e2l_w + 0 * 3 * DD, w_e2l_b + 0 * DD);

  u16* R = Pb0; u16* other = Pb1;
  for (int lv = 0; lv < 3; ++lv) {
    int wc = 1 + 2 * lv, wl = 2 + 2 * lv;
    // agg = affine_msg[lv](seg(h[from]))
    k_gather<<<NN, DD, 0, stream>>>(R, other, row_ptr, csr_src,
        stat_msg[lv], msg_bn_g + lv * DD, msg_bn_b + lv * DD);
    // P2 = relu(agg @ conv_w[lv] + conv_b + e2n[lv+1]); stats -> hid[lv]
    k_wprep<0><<<1, 256, 0, stream>>>(conv_w + (size_t)lv * DD * DD, conv_b + lv * DD,
        nullptr, nullptr, nullptr, nullptr, nullptr, nullptr, wt[wc], bp[wc], re[wc]);
    k_gemm<0><<<GEMM_GRID, 256, 0, stream>>>(other, wt[wc], bp[wc], Pb2, stat_hid[lv],
        nullptr, nullptr, agg_ef, deg,
        w_e2l_w + (size_t)(lv + 1) * 3 * DD, w_e2l_b + (lv + 1) * DD);
    // R_new = relu(norm_hid(P2) @ l2_w[lv] + l2_b + affine_msg[lv](R)); stats -> msg[lv+1]
    k_wprep<1><<<1, 256, 0, stream>>>(l2_w + (size_t)lv * DD * DD, l2_b + lv * DD,
        stat_hid[lv], hid_bn_g + lv * DD, hid_bn_b + lv * DD,
        stat_msg[lv], msg_bn_g + lv * DD, msg_bn_b + lv * DD, wt[wl], bp[wl], re[wl]);
    k_gemm<1><<<GEMM_GRID, 256, 0, stream>>>(Pb2, wt[wl], bp[wl], other, stat_msg[lv + 1],
        re[wl], R, nullptr, nullptr, nullptr, nullptr);
    u16* t = R; R = other; other = t;
  }

  k_segmax<<<(NN / 8) * DD / 256, 256, 0, stream>>>(
      R, g_idx, gemb, stat_msg[3], msg_bn_g + 3 * DD, msg_bn_b + 3 * DD);
  k_readout<<<GG, DD, 0, stream>>>(gemb, readout_w, readout_b, out);
}

// Round 3
// 704.658 us; speedup vs baseline: 4.3571x; 1.6035x over previous
//
#include <hip/hip_runtime.h>
#include <hip/hip_bf16.h>

#define NN 100000
#define NE 1600000
#define DD 128
#define GG 64
#define BN_EPS 1e-5f

typedef unsigned short u16;
using f32x4 = __attribute__((ext_vector_type(4))) float;
using s16x8 = __attribute__((ext_vector_type(8))) short;

constexpr int SCAN_B = 1024;
constexpr int NB = (NN + SCAN_B - 1) / SCAN_B;  // 98

__device__ __forceinline__ unsigned enc_f(float v) {
  unsigned u = __float_as_uint(v);
  return (u & 0x80000000u) ? ~u : (u | 0x80000000u);
}
__device__ __forceinline__ float dec_f(unsigned k) {
  unsigned u = (k & 0x80000000u) ? (k & 0x7FFFFFFFu) : ~k;
  return __uint_as_float(u);
}
__device__ __forceinline__ u16 f2b(float x) {
  __hip_bfloat16 h = __float2bfloat16(x);
  return *(u16*)&h;
}
__device__ __forceinline__ float b2f(u16 u) {
  unsigned v = ((unsigned)u) << 16;
  return __uint_as_float(v);
}

// ---------------- init: zero cursor + stats, segmax identity ----------------
__global__ void k_init(int* cursor, float* stats, unsigned* gemb_enc) {
  int i = blockIdx.x * blockDim.x + threadIdx.x;
  if (i < NN) cursor[i] = 0;
  if (i < 7*2*DD) stats[i] = 0.f;
  if (i < GG*DD) gemb_enc[i] = 0x007FFFFFu;  // enc(-inf)
}

// ---------------- fp32 -> bf16 convert (node features) ----------------
__global__ void k_cvt(const float4* __restrict__ in, u16* __restrict__ out) {
  int i = blockIdx.x * blockDim.x + threadIdx.x;
  if (i >= NN * DD / 4) return;
  float4 v = in[i];
  ushort4 o;
  o.x = f2b(v.x); o.y = f2b(v.y); o.z = f2b(v.z); o.w = f2b(v.w);
  *(ushort4*)(out + (size_t)i * 4) = o;
}

// ---------------- CSR build, pass 1: per-node slot via single atomic ----------------
// cursor[n] ends equal to in-degree(n).
__global__ void k_fill1(const int* __restrict__ to, int* cursor, int* __restrict__ tmp_pos) {
  int e = blockIdx.x * blockDim.x + threadIdx.x;
  if (e >= NE) return;
  tmp_pos[e] = atomicAdd(&cursor[to[e]], 1);
}

// ---------------- scan over cursor(=deg) -> exclusive row_ptr ----------------
__global__ void k_scan1(const int* __restrict__ deg, int* row_ptr, int* bsum) {
  __shared__ int lds[SCAN_B];
  int t = threadIdx.x, i = blockIdx.x * SCAN_B + t;
  int v = (i < NN) ? deg[i] : 0;
  lds[t] = v;
  __syncthreads();
  for (int off = 1; off < SCAN_B; off <<= 1) {
    int add = (t >= off) ? lds[t - off] : 0;
    __syncthreads();
    lds[t] += add;
    __syncthreads();
  }
  if (i < NN) row_ptr[i] = lds[t] - v;
  if (t == SCAN_B - 1) bsum[blockIdx.x] = lds[t];
}

__global__ void k_scan2(const int* bsum, int* boff, int* row_ptr) {
  if (blockIdx.x == 0 && threadIdx.x == 0) {
    int run = 0;
    for (int b = 0; b < NB; ++b) { boff[b] = run; run += bsum[b]; }
    row_ptr[NN] = run;
  }
}

__global__ void k_scan3(int* row_ptr, const int* __restrict__ boff) {
  int i = blockIdx.x * blockDim.x + threadIdx.x;
  if (i >= NN) return;
  row_ptr[i] += boff[i >> 10];
}

// ---------------- CSR build, pass 2: scatter (no atomics) ----------------
__global__ void k_fill2(const int* __restrict__ from, const int* __restrict__ to,
                        const int* __restrict__ tmp_pos, const int* __restrict__ row_ptr,
                        int* __restrict__ csr_src, int* __restrict__ csr_eid) {
  int e = blockIdx.x * blockDim.x + threadIdx.x;
  if (e >= NE) return;
  int pos = row_ptr[to[e]] + tmp_pos[e];
  csr_src[pos] = from[e];
  csr_eid[pos] = e;
}

// ---------------- per-node raw edge-feature aggregation (no atomics) ----------------
// agg4[n] = { sum_e ef[e][0..2], deg }
__global__ void k_node_ef(const float* __restrict__ ef, const int* __restrict__ row_ptr,
                          const int* __restrict__ csr_eid, float* __restrict__ agg4) {
  int t = blockIdx.x * blockDim.x + threadIdx.x;
  int n = t >> 2, c = t & 3;
  if (n >= NN) return;
  int s = row_ptr[n], e = row_ptr[n + 1];
  float acc;
  if (c < 3) {
    acc = 0.f;
    for (int i = s; i < e; ++i) {
      int eid = csr_eid[i];
      acc += ef[(size_t)eid * 3 + c];
    }
  } else {
    acc = (float)(e - s);
  }
  agg4[n * 4 + c] = acc;
}

// ---------------- neighbor gather: wave per node, 2 dims/lane ----------------
__global__ __launch_bounds__(256)
void k_gather(const u16* __restrict__ R, u16* __restrict__ out,
              const int* __restrict__ row_ptr, const int* __restrict__ csr_src,
              const float* __restrict__ stats, const float* __restrict__ g,
              const float* __restrict__ b) {
  const int wid = (blockIdx.x * 256 + threadIdx.x) >> 6;   // node
  if (wid >= NN) return;
  const int lane = threadIdx.x & 63;
  const int s = row_ptr[wid], e = row_ptr[wid + 1];
  const unsigned* R32 = (const unsigned*)R;
  float a0 = 0.f, a1 = 0.f;
  int i = s;
  for (; i + 3 < e; i += 4) {
    int s0 = csr_src[i], s1 = csr_src[i + 1], s2 = csr_src[i + 2], s3 = csr_src[i + 3];
    unsigned v0 = R32[(size_t)s0 * 64 + lane];
    unsigned v1 = R32[(size_t)s1 * 64 + lane];
    unsigned v2 = R32[(size_t)s2 * 64 + lane];
    unsigned v3 = R32[(size_t)s3 * 64 + lane];
    a0 += __uint_as_float(v0 << 16) + __uint_as_float(v1 << 16)
        + __uint_as_float(v2 << 16) + __uint_as_float(v3 << 16);
    a1 += __uint_as_float(v0 & 0xFFFF0000u) + __uint_as_float(v1 & 0xFFFF0000u)
        + __uint_as_float(v2 & 0xFFFF0000u) + __uint_as_float(v3 & 0xFFFF0000u);
  }
  for (; i < e; ++i) {
    unsigned v = R32[(size_t)csr_src[i] * 64 + lane];
    a0 += __uint_as_float(v << 16);
    a1 += __uint_as_float(v & 0xFFFF0000u);
  }
  const int d0 = lane * 2;
  float dg = (float)(e - s);
  float m0 = stats[d0] * (1.f / NN), m1 = stats[d0 + 1] * (1.f / NN);
  float v0 = stats[DD + d0] * (1.f / NN) - m0 * m0;
  float v1 = stats[DD + d0 + 1] * (1.f / NN) - m1 * m1;
  float sc0 = g[d0] * rsqrtf(v0 + BN_EPS), sc1 = g[d0 + 1] * rsqrtf(v1 + BN_EPS);
  float sh0 = b[d0] - m0 * sc0, sh1 = b[d0 + 1] - m1 * sc1;
  float r0 = sc0 * a0 + sh0 * dg;
  float r1 = sc1 * a1 + sh1 * dg;
  unsigned pk = (unsigned)f2b(r0) | ((unsigned)f2b(r1) << 16);
  ((unsigned*)out)[(size_t)wid * 64 + lane] = pk;
}

// ---------------- weight prep ----------------
// MODE 1 folds input-BN into weights; also precomputes residual affine into rese.
template<int MODE>
__device__ __forceinline__ void wprep_body(
    const float* __restrict__ W, const float* __restrict__ bias,
    const float* __restrict__ in_stats, const float* __restrict__ in_g,
    const float* __restrict__ in_b,
    const float* __restrict__ res_stats, const float* __restrict__ res_g,
    const float* __restrict__ res_b,
    u16* __restrict__ WT, float* __restrict__ biasP, float* __restrict__ rese) {
  __shared__ float s_s[DD], s_t[DD];
  int t = threadIdx.x;
  if (t < DD) {
    float s = 1.f, tt = 0.f;
    if (MODE == 1) {
      float mean = in_stats[t] * (1.f / NN);
      float var  = in_stats[DD + t] * (1.f / NN) - mean * mean;
      float rs = rsqrtf(var + BN_EPS);
      s = in_g[t] * rs;
      tt = in_b[t] - mean * s;
      float m2 = res_stats[t] * (1.f / NN);
      float v2 = res_stats[DD + t] * (1.f / NN) - m2 * m2;
      float r2 = rsqrtf(v2 + BN_EPS);
      float sc = res_g[t] * r2;
      rese[t] = sc;
      rese[DD + t] = res_b[t] - m2 * sc;
    }
    s_s[t] = s; s_t[t] = tt;
  }
  __syncthreads();
  for (int idx = t; idx < DD * DD; idx += 256) {
    int k = idx >> 7, n = idx & 127;
    WT[n * DD + k] = f2b(W[idx] * s_s[k]);
  }
  if (t < DD) {
    float acc = bias[t];
    if (MODE == 1)
      for (int k = 0; k < DD; ++k) acc += s_t[k] * W[k * DD + t];
    biasP[t] = acc;
  }
}

// all 4 MODE-0 weight preps in one launch (block 0: n2l, blocks 1..3: conv[lv])
__global__ void k_wprep0(const float* __restrict__ w_n2l_w, const float* __restrict__ w_n2l_b,
                         const float* __restrict__ conv_w, const float* __restrict__ conv_b,
                         u16* wt0, float* bp0, u16* wt1, float* bp1,
                         u16* wt3, float* bp3, u16* wt5, float* bp5) {
  int blk = blockIdx.x;
  const float* W; const float* bias; u16* WT; float* biasP;
  if (blk == 0)      { W = w_n2l_w;              bias = w_n2l_b;          WT = wt0; biasP = bp0; }
  else if (blk == 1) { W = conv_w;               bias = conv_b;           WT = wt1; biasP = bp1; }
  else if (blk == 2) { W = conv_w + DD * DD;     bias = conv_b + DD;      WT = wt3; biasP = bp3; }
  else               { W = conv_w + 2 * DD * DD; bias = conv_b + 2 * DD;  WT = wt5; biasP = bp5; }
  wprep_body<0>(W, bias, nullptr, nullptr, nullptr, nullptr, nullptr, nullptr,
                WT, biasP, nullptr);
}

__global__ void k_wprep1(const float* __restrict__ W, const float* __restrict__ bias,
                         const float* __restrict__ in_stats, const float* __restrict__ in_g,
                         const float* __restrict__ in_b,
                         const float* __restrict__ res_stats, const float* __restrict__ res_g,
                         const float* __restrict__ res_b,
                         u16* WT, float* biasP, float* rese) {
  wprep_body<1>(W, bias, in_stats, in_g, in_b, res_stats, res_g, res_b, WT, biasP, rese);
}

// swizzled LDS byte address: granule XOR within 8-granule (128B) halves of a 256B row
__device__ __forceinline__ int swz_addr(int row_bytes, int xr, int g, int o) {
  return row_bytes + ((((g & 7) ^ xr) | (g & 8)) << 4) + o;
}

// ---------------- MFMA GEMM ----------------
// MODE 0: extra = e2n from agg4 (agg_ef @ w_e2l + deg*b_e2l)   MODE 1: extra = affine(resid)
template<int MODE>
__global__ __launch_bounds__(256, 2)
void k_gemm(const u16* __restrict__ A, const u16* __restrict__ WT,
            const float* __restrict__ biasP, u16* __restrict__ out,
            float* __restrict__ stats_out,
            const float* __restrict__ rese, const u16* __restrict__ resid,
            const float4* __restrict__ agg4,
            const float* __restrict__ w_e2l, const float* __restrict__ b_e2l) {
  __shared__ u16 lds_a[128 * 128];   // 32 KB, swizzled
  __shared__ u16 lds_b[128 * 128];   // 32 KB, swizzled (WT = W^T, [n][k])
  __shared__ float sstats[2 * DD];
  const int tid  = threadIdx.x;
  const int lane = tid & 63;
  const int wv   = tid >> 6;
  const int row0 = blockIdx.x * 128;

  if (tid < 2 * DD) sstats[tid] = 0.f;

#pragma unroll
  for (int c = 0; c < 8; ++c) {
    int gidx = (wv * 8 + c) * 64 + lane;
    int row = gidx >> 4, gL = gidx & 15;
    int gS = (gL & 8) | ((gL & 7) ^ (row & 7));
    int arow = row0 + row; if (arow >= NN) arow = NN - 1;
    const u16* gsrcA = A  + (size_t)arow * DD + gS * 8;
    const u16* gsrcB = WT + (size_t)row  * DD + gS * 8;
    u16* ldstA = lds_a + (size_t)(wv * 8 + c) * 512;
    u16* ldstB = lds_b + (size_t)(wv * 8 + c) * 512;
    __builtin_amdgcn_global_load_lds(
        (const __attribute__((address_space(1))) unsigned int*)gsrcA,
        (__attribute__((address_space(3))) unsigned int*)ldstA, 16, 0, 0);
    __builtin_amdgcn_global_load_lds(
        (const __attribute__((address_space(1))) unsigned int*)gsrcB,
        (__attribute__((address_space(3))) unsigned int*)ldstB, 16, 0, 0);
  }
  __syncthreads();

  const int colid = lane & 15;
  const int lgrp  = lane >> 4;
  const int rowbase = wv * 32;
  const int o = (lgrp & 1) * 8;

  s16x8 afr[2][4];
#pragma unroll
  for (int rf = 0; rf < 2; ++rf) {
    int r = rowbase + rf * 16 + colid;
    int rb = r << 8, xr = r & 7;
#pragma unroll
    for (int ks = 0; ks < 4; ++ks) {
      int g0 = ks * 4 + (lgrp >> 1);
      uint2 lo = *(const uint2*)((const char*)lds_a + swz_addr(rb, xr, g0, o));
      uint2 hi = *(const uint2*)((const char*)lds_a + swz_addr(rb, xr, g0 + 2, o));
      union { unsigned u[4]; s16x8 v; } pk;
      pk.u[0] = lo.x; pk.u[1] = lo.y; pk.u[2] = hi.x; pk.u[3] = hi.y;
      afr[rf][ks] = pk.v;
    }
  }

  float4 ev[2][4];
  if (MODE == 0) {
#pragma unroll
    for (int rf = 0; rf < 2; ++rf)
#pragma unroll
      for (int q = 0; q < 4; ++q) {
        int r = row0 + rowbase + rf * 16 + lgrp * 4 + q;
        if (r >= NN) r = NN - 1;
        ev[rf][q] = agg4[r];
      }
  }

  for (int cf = 0; cf < 8; ++cf) {
    const int col = cf * 16 + colid;
    float bp = biasP[col];
    f32x4 acc0, acc1;
    if (MODE == 1) {
      float sc = rese[col], sh = rese[DD + col];
#pragma unroll
      for (int rf = 0; rf < 2; ++rf)
#pragma unroll
        for (int q = 0; q < 4; ++q) {
          int r = row0 + rowbase + rf * 16 + lgrp * 4 + q;
          int rc = r < NN ? r : NN - 1;
          float v = bp + sc * b2f(resid[(size_t)rc * DD + col]) + sh;
          if (rf == 0) acc0[q] = v; else acc1[q] = v;
        }
    } else {
      float we0 = w_e2l[col], we1 = w_e2l[DD + col], we2 = w_e2l[2 * DD + col];
      float be = b_e2l[col];
#pragma unroll
      for (int rf = 0; rf < 2; ++rf)
#pragma unroll
        for (int q = 0; q < 4; ++q) {
          float4 e4 = ev[rf][q];
          float v = bp + e4.x * we0 + e4.y * we1 + e4.z * we2 + e4.w * be;
          if (rf == 0) acc0[q] = v; else acc1[q] = v;
        }
    }
    {
      int nb = col << 8, xn = col & 7;
#pragma unroll
      for (int ks = 0; ks < 4; ++ks) {
        int g0 = ks * 4 + (lgrp >> 1);
        uint2 lo = *(const uint2*)((const char*)lds_b + swz_addr(nb, xn, g0, o));
        uint2 hi = *(const uint2*)((const char*)lds_b + swz_addr(nb, xn, g0 + 2, o));
        union { unsigned u[4]; s16x8 v; } pk;
        pk.u[0] = lo.x; pk.u[1] = lo.y; pk.u[2] = hi.x; pk.u[3] = hi.y;
        acc0 = __builtin_amdgcn_mfma_f32_16x16x32_bf16(afr[0][ks], pk.v, acc0, 0, 0, 0);
        acc1 = __builtin_amdgcn_mfma_f32_16x16x32_bf16(afr[1][ks], pk.v, acc1, 0, 0, 0);
      }
    }
    float s = 0.f, s2 = 0.f;
#pragma unroll
    for (int rf = 0; rf < 2; ++rf)
#pragma unroll
      for (int q = 0; q < 4; ++q) {
        int r = row0 + rowbase + rf * 16 + lgrp * 4 + q;
        float v = fmaxf(rf == 0 ? acc0[q] : acc1[q], 0.f);
        if (r < NN) {
          out[(size_t)r * DD + col] = f2b(v);
          s += v; s2 += v * v;
        }
      }
    s  += __shfl_xor(s, 16);  s  += __shfl_xor(s, 32);
    s2 += __shfl_xor(s2, 16); s2 += __shfl_xor(s2, 32);
    if (lgrp == 0) {
      atomicAdd(&sstats[col], s);
      atomicAdd(&sstats[DD + col], s2);
    }
  }
  __syncthreads();
  if (tid < 2 * DD) atomicAdd(&stats_out[tid], sstats[tid]);
}

// ---------------- segment max (bf16 input) ----------------
__global__ void k_segmax(const u16* __restrict__ R, const int* __restrict__ g_idx,
                         unsigned* __restrict__ gemb_enc,
                         const float* __restrict__ stats, const float* __restrict__ g,
                         const float* __restrict__ b) {
  int t = blockIdx.x * blockDim.x + threadIdx.x;
  int d = t & (DD - 1);
  int chunk = t >> 7;
  int n0 = chunk * 8;
  if (n0 >= NN) return;
  float mean = stats[d] * (1.f / NN);
  float var  = stats[DD + d] * (1.f / NN) - mean * mean;
  float rs = rsqrtf(var + BN_EPS);
  float scale = g[d] * rs;
  float shift = b[d] - mean * scale;
  int cur = -1; float run = 0.f;
  int nend = n0 + 8; if (nend > NN) nend = NN;
  for (int n = n0; n < nend; ++n) {
    float v = scale * b2f(R[(size_t)n * DD + d]) + shift;
    int gi = g_idx[n];
    if (gi != cur) {
      if (cur >= 0) atomicMax(&gemb_enc[cur * DD + d], enc_f(run));
      cur = gi; run = v;
    } else {
      run = fmaxf(run, v);
    }
  }
  if (cur >= 0) atomicMax(&gemb_enc[cur * DD + d], enc_f(run));
}

// ---------------- readout ----------------
__global__ void k_readout(const unsigned* __restrict__ gemb,
                          const float* __restrict__ W, const float* __restrict__ b,
                          float* __restrict__ out) {
  __shared__ float row[DD];
  int g = blockIdx.x, t = threadIdx.x;
  row[t] = dec_f(gemb[g * DD + t]);
  __syncthreads();
  float acc = b[t];
  for (int d = 0; d < DD; ++d) acc += row[d] * W[d * DD + t];
  out[g * DD + t] = fmaxf(acc, 0.f);
}

extern "C" void kernel_launch(void* const* d_in, const int* in_sizes, int n_in,
                              void* d_out, int out_size, void* d_ws, size_t ws_size,
                              hipStream_t stream) {
  const float* node_feat = (const float*)d_in[0];
  const float* edge_feat = (const float*)d_in[1];
  const int*   efrom     = (const int*)d_in[2];
  const int*   eto       = (const int*)d_in[3];
  const int*   g_idx     = (const int*)d_in[4];
  const float* w_n2l_w   = (const float*)d_in[6];
  const float* w_n2l_b   = (const float*)d_in[7];
  const float* w_e2l_w   = (const float*)d_in[8];   // [4][3][128]
  const float* w_e2l_b   = (const float*)d_in[9];   // [4][128]
  const float* conv_w    = (const float*)d_in[10];  // [3][128][128]
  const float* conv_b    = (const float*)d_in[11];
  const float* l2_w      = (const float*)d_in[12];
  const float* l2_b      = (const float*)d_in[13];
  const float* msg_bn_g  = (const float*)d_in[14];  // [4][128]
  const float* msg_bn_b  = (const float*)d_in[15];
  const float* hid_bn_g  = (const float*)d_in[16];  // [3][128]
  const float* hid_bn_b  = (const float*)d_in[17];
  const float* readout_w = (const float*)d_in[18];
  const float* readout_b = (const float*)d_in[19];
  float* out = (float*)d_out;
  (void)in_sizes; (void)n_in; (void)out_size; (void)ws_size;

  char* ws = (char*)d_ws;
  size_t off = 0;
  auto alloc = [&](size_t bytes) -> void* {
    void* p = ws + off; off += (bytes + 511) & ~(size_t)511; return p;
  };
  u16*      node_bf = (u16*)alloc((size_t)NN * DD * 2);
  u16*      Pb0     = (u16*)alloc((size_t)NN * DD * 2);
  u16*      Pb1     = (u16*)alloc((size_t)NN * DD * 2);
  u16*      Pb2     = (u16*)alloc((size_t)NN * DD * 2);
  float*    agg4    = (float*)alloc((size_t)NN * 4 * 4);
  int*      cursor  = (int*)alloc((size_t)NN * 4);
  int*      row_ptr = (int*)alloc((size_t)(NN + 1) * 4);
  int*      tmp_pos = (int*)alloc((size_t)NE * 4);
  int*      csr_src = (int*)alloc((size_t)NE * 4);
  int*      csr_eid = (int*)alloc((size_t)NE * 4);
  int*      bsum    = (int*)alloc((size_t)NB * 4);
  int*      boff    = (int*)alloc((size_t)NB * 4);
  float*    stats   = (float*)alloc((size_t)7 * 2 * DD * 4);
  unsigned* gemb    = (unsigned*)alloc((size_t)GG * DD * 4);
  u16*      wt[7];
  float*    bp[7];
  float*    re[7];
  for (int i = 0; i < 7; ++i) {
    wt[i] = (u16*)alloc((size_t)DD * DD * 2);
    bp[i] = (float*)alloc((size_t)DD * 4);
    re[i] = (float*)alloc((size_t)2 * DD * 4);
  }

  k_init<<<(NN + 255) / 256, 256, 0, stream>>>(cursor, stats, gemb);
  k_cvt<<<(NN * DD / 4 + 255) / 256, 256, 0, stream>>>((const float4*)node_feat, node_bf);
  k_fill1<<<(NE + 255) / 256, 256, 0, stream>>>(eto, cursor, tmp_pos);
  k_scan1<<<NB, SCAN_B, 0, stream>>>(cursor, row_ptr, bsum);
  k_scan2<<<1, 64, 0, stream>>>(bsum, boff, row_ptr);
  k_scan3<<<(NN + 255) / 256, 256, 0, stream>>>(row_ptr, boff);
  k_fill2<<<(NE + 255) / 256, 256, 0, stream>>>(efrom, eto, tmp_pos, row_ptr,
                                                csr_src, csr_eid);
  k_node_ef<<<(NN * 4 + 255) / 256, 256, 0, stream>>>(edge_feat, row_ptr, csr_eid,
                                                      agg4);
  k_wprep0<<<4, 256, 0, stream>>>(w_n2l_w, w_n2l_b, conv_w, conv_b,
                                  wt[0], bp[0], wt[1], bp[1], wt[3], bp[3], wt[5], bp[5]);

  float* stat_msg[4] = { stats + 0*256, stats + 1*256, stats + 2*256, stats + 3*256 };
  float* stat_hid[3] = { stats + 4*256, stats + 5*256, stats + 6*256 };
  const int GEMM_GRID = (NN + 127) / 128;  // 782

  // GEMM0: P0 = relu(node @ w_n2l + b + e2n0); stats -> msg[0]
  k_gemm<0><<<GEMM_GRID, 256, 0, stream>>>(node_bf, wt[0], bp[0], Pb0, stat_msg[0],
      nullptr, nullptr, (const float4*)agg4, w_e2l_w + 0 * 3 * DD, w_e2l_b + 0 * DD);

  u16* R = Pb0; u16* other = Pb1;
  for (int lv = 0; lv < 3; ++lv) {
    int wc = 1 + 2 * lv, wl = 2 + 2 * lv;
    // agg = affine_msg[lv](seg(h[from]))
    k_gather<<<(NN * 64 + 255) / 256, 256, 0, stream>>>(R, other, row_ptr, csr_src,
        stat_msg[lv], msg_bn_g + lv * DD, msg_bn_b + lv * DD);
    // P2 = relu(agg @ conv_w[lv] + conv_b + e2n[lv+1]); stats -> hid[lv]
    k_gemm<0><<<GEMM_GRID, 256, 0, stream>>>(other, wt[wc], bp[wc], Pb2, stat_hid[lv],
        nullptr, nullptr, (const float4*)agg4,
        w_e2l_w + (size_t)(lv + 1) * 3 * DD, w_e2l_b + (lv + 1) * DD);
    // R_new = relu(norm_hid(P2) @ l2_w[lv] + l2_b + affine_msg[lv](R)); stats -> msg[lv+1]
    k_wprep1<<<1, 256, 0, stream>>>(l2_w + (size_t)lv * DD * DD, l2_b + lv * DD,
        stat_hid[lv], hid_bn_g + lv * DD, hid_bn_b + lv * DD,
        stat_msg[lv], msg_bn_g + lv * DD, msg_bn_b + lv * DD, wt[wl], bp[wl], re[wl]);
    k_gemm<1><<<GEMM_GRID, 256, 0, stream>>>(Pb2, wt[wl], bp[wl], other, stat_msg[lv + 1],
        re[wl], R, nullptr, nullptr, nullptr);
    u16* t = R; R = other; other = t;
  }

  k_segmax<<<(NN / 8) * DD / 256, 256, 0, stream>>>(
      R, g_idx, gemb, stat_msg[3], msg_bn_g + 3 * DD, msg_bn_b + 3 * DD);
  k_readout<<<GG, DD, 0, stream>>>(gemb, readout_w, readout_b, out);
}